// Round 17
// baseline (192.999 us; speedup 1.0000x reference)
//
#include <hip/hip_runtime.h>
#include <hip/hip_fp16.h>

#define NG    32
#define DG    64
#define NPL   64
#define CPD2  16               // sort granularity (fine cells)
#define NC2   4096             // 16^3 sort bins
#define NCELL 512              // gather cells (8^3)
#define NPAIR (NCELL * NG)     // 16384 (cell,grid) pairs
#define HPAD  16               // ints per padded counter (64B line)
#define BS    512
#define TV    4096             // 16^3 voxels per tile
#define HS    72               // mlp sH row stride (f16): 144B = 16B-aligned rows

// tile bank swizzle: XOR z-bits into bank bits; same on write and read.
#define SWZ(i) ((i) ^ (((i) >> 6) & 28))

typedef _Float16 half8 __attribute__((ext_vector_type(8)));
typedef float    floatx4 __attribute__((ext_vector_type(4)));

// ---------------------------------------------------------------------------
// Morton helpers
// ---------------------------------------------------------------------------
__device__ __forceinline__ int morton16(int cx, int cy, int cz) {
    int m = 0;
    #pragma unroll
    for (int b = 0; b < 4; ++b)
        m |= (((cx >> b) & 1) << (3 * b))
           | (((cy >> b) & 1) << (3 * b + 1))
           | (((cz >> b) & 1) << (3 * b + 2));
    return m;
}
__device__ __forceinline__ int cell_of(float px, float py, float pz) {
    int cx = min(max((int)((px + 1.0f) * (0.5f * CPD2)), 0), CPD2 - 1);
    int cy = min(max((int)((py + 1.0f) * (0.5f * CPD2)), 0), CPD2 - 1);
    int cz = min(max((int)((pz + 1.0f) * (0.5f * CPD2)), 0), CPD2 - 1);
    return morton16(cx, cy, cz);
}

// ---------------------------------------------------------------------------
// Prelude4: fused pack + hist + classify with INTERLEAVED block roles.
// Special blocks (hist / classify) at (bid&7)==7, bid>>3 < nHist+1 — they
// start at t~0 and overlap the pack stream instead of queuing behind it.
// ---------------------------------------------------------------------------
__global__ __launch_bounds__(256)
void prelude4_kernel(const float4* __restrict__ fga, uint4* __restrict__ pg,
                     int nHist,
                     const float* __restrict__ x, int N,
                     int* __restrict__ ghist,
                     const float* __restrict__ scales,
                     const float* __restrict__ trans,
                     unsigned* __restrict__ pairs, int* __restrict__ counters)
{
    __shared__ int lh[NC2];                  // hist/classify branches only
    const int tid = threadIdx.x;
    const int bid = blockIdx.x;

    const int  nSpecial = nHist + 1;
    const bool special  = ((bid & 7) == 7) && ((bid >> 3) < nSpecial);
    const int  sidx     = bid >> 3;                      // special index
    // pack index = bid minus number of special blocks with id < bid
    const int  packIdx  = bid - min(bid >> 3, nSpecial);

    if (!special) {
        // ---- pack: 1024 uint4 per block, lane-interleaved ----
        const int base4 = packIdx * 1024;
        int   idx[4];
        float4 a[4], b[4];
        #pragma unroll
        for (int k = 0; k < 4; ++k) {
            idx[k] = base4 + k * 256 + tid;
            int g  = idx[k] >> 16;
            int v4 = idx[k] & 65535;
            const float4* p0 = fga + ((size_t)g << 17) + v4;  // ch0 plane
            a[k] = p0[0];
            b[k] = p0[1 << 16];                               // ch1 plane
        }
        #pragma unroll
        for (int k = 0; k < 4; ++k) {
            uint4 o;
            __half2 h;
            h = __floats2half2_rn(a[k].x, b[k].x); o.x = *(unsigned*)&h;
            h = __floats2half2_rn(a[k].y, b[k].y); o.y = *(unsigned*)&h;
            h = __floats2half2_rn(a[k].z, b[k].z); o.z = *(unsigned*)&h;
            h = __floats2half2_rn(a[k].w, b[k].w); o.w = *(unsigned*)&h;
            pg[idx[k]] = o;
        }
        return;
    }

    if (sidx < nHist) {
        // ---- hist (2048 points per block) ----
        for (int i = tid; i < NC2; i += 256) lh[i] = 0;
        __syncthreads();
        int base = sidx * 2048 + tid;
        #pragma unroll
        for (int s = 0; s < 8; ++s) {
            int n = base + s * 256;
            if (n < N) atomicAdd(&lh[cell_of(x[3*n], x[3*n+1], x[3*n+2])], 1);
        }
        __syncthreads();
        for (int i = tid; i < NC2; i += 256) {
            int c = lh[i];
            if (c) atomicAdd(&ghist[i * HPAD], c);
        }
        return;
    }

    // ---- classify block (lh[0..1] = head/tail) ----
    __shared__ float sA[NG * 3], sB[NG * 3];
    const int lane = tid & 63;
    if (tid == 0) { lh[0] = 0; lh[1] = NPAIR; }
    if (tid < NG * 3) {
        const float k = (1.0f / 1.48f) * 31.5f;
        sA[tid] = scales[tid] * k;
        sB[tid] = trans[tid] * k + 31.5f;
    }
    __syncthreads();

    for (int p = tid; p < NPAIR; p += 256) {
        int c = p >> 5, g = p & 31;
        int cx = (c & 1)        | (((c >> 3) & 1) << 1) | (((c >> 6) & 1) << 2);
        int cy = ((c >> 1) & 1) | (((c >> 4) & 1) << 1) | (((c >> 7) & 1) << 2);
        int cz = ((c >> 2) & 1) | (((c >> 5) & 1) << 1) | (((c >> 8) & 1) << 2);
        bool skip = false, fast = true;
        #pragma unroll
        for (int d = 0; d < 3; ++d) {
            float A = sA[3 * g + d], B = sB[3 * g + d];
            int  cc = (d == 0) ? cx : ((d == 1) ? cy : cz);
            float lo = fmaf((float)cc, 0.25f, -1.0f) - 1e-4f;
            float hi = lo + 0.25f + 2e-4f;
            float fmn = fmaf(lo, A, B);       // A > 0 (scales > 0)
            float fmx = fmaf(hi, A, B);
            skip = skip || (fmx <= -1.0f) || (fmn >= 64.0f);
            fast = fast && (fmn >= 0.0f) && (fmx <= 62.9f);
        }
        unsigned code = ((unsigned)c << 6) | ((unsigned)g << 1) | (fast ? 1u : 0u);

        unsigned long long mAct = __ballot(!skip);
        int cntA = __popcll(mAct);
        int bA = 0, bS = 0;
        if (lane == 0) {
            bA = atomicAdd(&lh[0], cntA);
            bS = atomicAdd(&lh[1], -(64 - cntA));
        }
        bA = __shfl(bA, 0); bS = __shfl(bS, 0);
        unsigned long long below = (1ull << lane) - 1ull;
        if (!skip) pairs[bA + __popcll(mAct & below)] = code;
        else       pairs[bS - 1 - __popcll(~mAct & below)] = code;
    }
    __syncthreads();
    if (tid == 0) counters[0] = lh[0];
}

// ---------------------------------------------------------------------------
// Scan (1 block, 1024 threads)
// ---------------------------------------------------------------------------
__global__ __launch_bounds__(1024)
void scan_kernel(const int* __restrict__ ghist, int* __restrict__ gcursor,
                 int* __restrict__ cellstart) {
    __shared__ int tsum[1024];
    int t = threadIdx.x;
    int v0 = ghist[(t * 4 + 0) * HPAD];
    int v1 = ghist[(t * 4 + 1) * HPAD];
    int v2 = ghist[(t * 4 + 2) * HPAD];
    int v3 = ghist[(t * 4 + 3) * HPAD];
    tsum[t] = v0 + v1 + v2 + v3;
    __syncthreads();
    #pragma unroll
    for (int off = 1; off < 1024; off <<= 1) {
        int u = (t >= off) ? tsum[t - off] : 0;
        __syncthreads();
        tsum[t] += u;
        __syncthreads();
    }
    int base = (t == 0) ? 0 : tsum[t - 1];
    gcursor[(t*4+0)*HPAD] = base; cellstart[t*4+0] = base; base += v0;
    gcursor[(t*4+1)*HPAD] = base; cellstart[t*4+1] = base; base += v1;
    gcursor[(t*4+2)*HPAD] = base; cellstart[t*4+2] = base; base += v2;
    gcursor[(t*4+3)*HPAD] = base; cellstart[t*4+3] = base;
    if (t == 1023) cellstart[NC2] = tsum[1023];
}

__global__ __launch_bounds__(BS)
void scatter_kernel(const float* __restrict__ x, int N,
                    int* __restrict__ gcursor, float4* __restrict__ sorted,
                    int* __restrict__ nidx) {
    __shared__ int cnt[NC2];
    __shared__ int base[NC2];
    int tid = threadIdx.x;
    for (int i = tid; i < NC2; i += BS) cnt[i] = 0;
    __syncthreads();
    int n = blockIdx.x * BS + tid;
    float px = 0.f, py = 0.f, pz = 0.f;
    int c = 0, r = 0;
    bool act = (n < N);
    if (act) {
        px = x[3*n]; py = x[3*n+1]; pz = x[3*n+2];
        c = cell_of(px, py, pz);
        r = atomicAdd(&cnt[c], 1);
    }
    __syncthreads();
    for (int i = tid; i < NC2; i += BS) {
        int cc = cnt[i];
        base[i] = cc ? atomicAdd(&gcursor[i * HPAD], cc) : 0;
    }
    __syncthreads();
    if (act) {
        int pos = base[c] + r;
        sorted[pos] = make_float4(px, py, pz, 0.0f);
        nidx[pos]   = n;
    }
}

// ---------------------------------------------------------------------------
__device__ __forceinline__ float2 h2_to_f2(unsigned u) {
    __half2 h = *reinterpret_cast<__half2*>(&u);
    return __half22float2(h);
}

template<bool FAST>
__device__ __forceinline__ unsigned sample_tile(
    const unsigned* __restrict__ tl,
    float px, float py, float pz,
    float A0, float A1, float A2, float B0, float B1, float B2,
    int ox, int oy, int oz)
{
    float fx = fmaf(px, A0, B0);
    float fy = fmaf(py, A1, B1);
    float fz = fmaf(pz, A2, B2);
    float flx = floorf(fx), fly = floorf(fy), flz = floorf(fz);
    int x0 = (int)flx, y0 = (int)fly, z0 = (int)flz;
    float wx = fx - flx, wy = fy - fly, wz = fz - flz;

    float wxa0, wxa1, wya0, wya1, wza0, wza1;
    int ix0, ix1, iy0, iy1, iz0, iz1;
    if (FAST) {
        wxa0 = 1.0f - wx; wxa1 = wx;
        wya0 = 1.0f - wy; wya1 = wy;
        wza0 = 1.0f - wz; wza1 = wz;
        ix0 = x0 - ox;            ix1 = ix0 + 1;
        iy0 = (y0 - oy) << 4;     iy1 = iy0 + 16;
        iz0 = (z0 - oz) << 8;     iz1 = iz0 + 256;
    } else {
        wxa0 = (x0 >= 0  && x0     < DG) ? (1.0f - wx) : 0.0f;
        wxa1 = (x0 >= -1 && x0 + 1 < DG) ? wx          : 0.0f;
        wya0 = (y0 >= 0  && y0     < DG) ? (1.0f - wy) : 0.0f;
        wya1 = (y0 >= -1 && y0 + 1 < DG) ? wy          : 0.0f;
        wza0 = (z0 >= 0  && z0     < DG) ? (1.0f - wz) : 0.0f;
        wza1 = (z0 >= -1 && z0 + 1 < DG) ? wz          : 0.0f;
        ix0 = min(max(x0     - ox, 0), 15);
        ix1 = min(max(x0 + 1 - ox, 0), 15);
        iy0 = (min(max(y0     - oy, 0), 15)) << 4;
        iy1 = (min(max(y0 + 1 - oy, 0), 15)) << 4;
        iz0 = (min(max(z0     - oz, 0), 15)) << 8;
        iz1 = (min(max(z0 + 1 - oz, 0), 15)) << 8;
    }
    const int m0 = (iz0 >> 6) & 28;
    const int m1 = (iz1 >> 6) & 28;

    float w00 = wya0 * wza0, w10 = wya1 * wza0;
    float w01 = wya0 * wza1, w11 = wya1 * wza1;

    float c0 = 0.0f, c1 = 0.0f;
    float2 v;
    v = h2_to_f2(tl[(iz0+iy0+ix0)^m0]); c0 = fmaf(wxa0*w00, v.x, c0); c1 = fmaf(wxa0*w00, v.y, c1);
    v = h2_to_f2(tl[(iz0+iy0+ix1)^m0]); c0 = fmaf(wxa1*w00, v.x, c0); c1 = fmaf(wxa1*w00, v.y, c1);
    v = h2_to_f2(tl[(iz0+iy1+ix0)^m0]); c0 = fmaf(wxa0*w10, v.x, c0); c1 = fmaf(wxa0*w10, v.y, c1);
    v = h2_to_f2(tl[(iz0+iy1+ix1)^m0]); c0 = fmaf(wxa1*w10, v.x, c0); c1 = fmaf(wxa1*w10, v.y, c1);
    v = h2_to_f2(tl[(iz1+iy0+ix0)^m1]); c0 = fmaf(wxa0*w01, v.x, c0); c1 = fmaf(wxa0*w01, v.y, c1);
    v = h2_to_f2(tl[(iz1+iy0+ix1)^m1]); c0 = fmaf(wxa1*w01, v.x, c0); c1 = fmaf(wxa1*w01, v.y, c1);
    v = h2_to_f2(tl[(iz1+iy1+ix0)^m1]); c0 = fmaf(wxa0*w11, v.x, c0); c1 = fmaf(wxa0*w11, v.y, c1);
    v = h2_to_f2(tl[(iz1+iy1+ix1)^m1]); c0 = fmaf(wxa1*w11, v.x, c0); c1 = fmaf(wxa1*w11, v.y, c1);

    __half2 hv = __floats2half2_rn(c0, c1);
    return *reinterpret_cast<unsigned*>(&hv);
}

// ---------------------------------------------------------------------------
// Gather: one 512-thread block per (cell,grid) pair; staged from PACKED grids.
// ---------------------------------------------------------------------------
__global__ __launch_bounds__(BS)
void gather2_kernel(const float4* __restrict__ sorted,
                    const int*   __restrict__ cs16,
                    const unsigned* __restrict__ pairs,
                    const int*   __restrict__ counters,
                    const float* __restrict__ scales,
                    const float* __restrict__ trans,
                    const unsigned* __restrict__ pg,
                    unsigned* __restrict__ fb, int N)
{
    __shared__ unsigned tile[TV];           // 16 KB

    const int tid = threadIdx.x;
    const int nA  = counters[0];
    unsigned pr   = pairs[blockIdx.x];
    const int c   = pr >> 6;
    const int g   = (pr >> 1) & 31;
    const bool fastp = pr & 1;

    int s0 = cs16[c * 8];
    int e  = cs16[c * 8 + 8];

    if ((int)blockIdx.x >= nA) {            // skipped pair: zero-fill
        for (int i = s0 + tid; i < e; i += BS) fb[(size_t)g * N + i] = 0u;
        return;
    }
    if (s0 >= e) return;

    int cx = (c & 1)        | (((c >> 3) & 1) << 1) | (((c >> 6) & 1) << 2);
    int cy = ((c >> 1) & 1) | (((c >> 4) & 1) << 1) | (((c >> 7) & 1) << 2);
    int cz = ((c >> 2) & 1) | (((c >> 5) & 1) << 1) | (((c >> 8) & 1) << 2);

    const float k = (1.0f / 1.48f) * 31.5f;
    float A0 = scales[3*g+0] * k, B0 = trans[3*g+0] * k + 31.5f;
    float A1 = scales[3*g+1] * k, B1 = trans[3*g+1] * k + 31.5f;
    float A2 = scales[3*g+2] * k, B2 = trans[3*g+2] * k + 31.5f;
    int ox = min(max((int)floorf(fmaf((float)cx * 0.25f - 1.0f, A0, B0)), 0), 48);
    int oy = min(max((int)floorf(fmaf((float)cy * 0.25f - 1.0f, A1, B1)), 0), 48);
    int oz = min(max((int)floorf(fmaf((float)cz * 0.25f - 1.0f, A2, B2)), 0), 48);

    float4 q0, q1, q2;
    int  i0 = s0 + tid, i1 = s0 + BS + tid, i2 = s0 + 2 * BS + tid;
    bool a0_ = (i0 < e), a1_ = (i1 < e), a2_ = (i2 < e);
    q0 = a0_ ? sorted[i0] : make_float4(0,0,0,0);
    q1 = a1_ ? sorted[i1] : make_float4(0,0,0,0);
    q2 = a2_ ? sorted[i2] : make_float4(0,0,0,0);

    const unsigned* gb = pg + ((size_t)g << 18);
    #pragma unroll
    for (int jj = 0; jj < 8; ++jj) {
        int v = tid + (jj << 9);
        tile[SWZ(v)] = gb[((oz + (v >> 8)) << 12) + ((oy + ((v >> 4) & 15)) << 6)
                          + ox + (v & 15)];
    }
    __syncthreads();

    unsigned* dst = fb + (size_t)g * N;
    if (fastp) {
        if (a0_) dst[i0] = sample_tile<true >(tile, q0.x,q0.y,q0.z, A0,A1,A2,B0,B1,B2, ox,oy,oz);
        if (a1_) dst[i1] = sample_tile<true >(tile, q1.x,q1.y,q1.z, A0,A1,A2,B0,B1,B2, ox,oy,oz);
        if (a2_) dst[i2] = sample_tile<true >(tile, q2.x,q2.y,q2.z, A0,A1,A2,B0,B1,B2, ox,oy,oz);
    } else {
        if (a0_) dst[i0] = sample_tile<false>(tile, q0.x,q0.y,q0.z, A0,A1,A2,B0,B1,B2, ox,oy,oz);
        if (a1_) dst[i1] = sample_tile<false>(tile, q1.x,q1.y,q1.z, A0,A1,A2,B0,B1,B2, ox,oy,oz);
        if (a2_) dst[i2] = sample_tile<false>(tile, q2.x,q2.y,q2.z, A0,A1,A2,B0,B1,B2, ox,oy,oz);
    }
}

// ---------------------------------------------------------------------------
// MFMA MLP with LDS union (r16): weight staging region reused as H bounce.
// ---------------------------------------------------------------------------
#define MBS 256
__global__ __launch_bounds__(MBS, 3)
void mlp_kernel(const unsigned* __restrict__ fb,
                const int* __restrict__ nidx,
                const float* __restrict__ W0, const float* __restrict__ b0,
                const float* __restrict__ W1, const float* __restrict__ b1,
                const float* __restrict__ W2, const float* __restrict__ b2,
                float* __restrict__ out, int N)
{
    __shared__ __align__(16) _Float16 smem[4 * NPL * HS];   // 36,864 B
    __shared__ float sb0f[NPL], sb1f[NPL], sW2f[NPL];

    int tid = threadIdx.x;
    _Float16* sW0h = smem;
    _Float16* sW1h = smem + NPL * NPL;
    for (int i = tid; i < NPL * NPL; i += MBS) {
        sW0h[i] = (_Float16)W0[i];
        sW1h[i] = (_Float16)W1[i];
    }
    if (tid < NPL) { sb0f[tid] = b0[tid]; sb1f[tid] = b1[tid]; sW2f[tid] = W2[tid]; }
    __syncthreads();

    const int wave = tid >> 6;
    const int lane = tid & 63;
    const int l15  = lane & 15;
    const int kg   = lane >> 4;
    const long wbase = (long)blockIdx.x * MBS + wave * 64;
    const bool active = (wbase < N);

    half8 B0f[4][2], B1f[4][2];
    float bias0[4], bias1[4], w2v[4];
    #pragma unroll
    for (int nt = 0; nt < 4; ++nt) {
        int ch = nt * 16 + l15;
        #pragma unroll
        for (int kh = 0; kh < 2; ++kh) {
            int k = kh * 32 + kg * 8;
            B0f[nt][kh] = *(const half8*)&sW0h[ch * NPL + k];
            B1f[nt][kh] = *(const half8*)&sW1h[ch * NPL + k];
        }
        bias0[nt] = sb0f[ch];
        bias1[nt] = sb1f[ch];
        w2v[nt]   = sW2f[ch];
    }
    __syncthreads();            // weights read; smem region reusable
    if (!active) return;

    _Float16* H = &smem[wave * NPL * HS];

    // ---- layer 0: A from 8 u32 planes ----
    floatx4 acc[4][4];
    #pragma unroll
    for (int mt = 0; mt < 4; ++mt) {
        long pt = wbase + mt * 16 + l15;
        if (pt > N - 1) pt = N - 1;
        const unsigned* p0 = fb + (size_t)(4 * kg) * N + pt;
        const unsigned* p1 = fb + (size_t)(16 + 4 * kg) * N + pt;
        uint4 t0 = make_uint4(p0[0], p0[N], p0[2*(size_t)N], p0[3*(size_t)N]);
        uint4 t1 = make_uint4(p1[0], p1[N], p1[2*(size_t)N], p1[3*(size_t)N]);
        half8 a0 = *reinterpret_cast<half8*>(&t0);
        half8 a1 = *reinterpret_cast<half8*>(&t1);
        #pragma unroll
        for (int nt = 0; nt < 4; ++nt) {
            floatx4 cc = {0.f, 0.f, 0.f, 0.f};
            cc = __builtin_amdgcn_mfma_f32_16x16x32_f16(a0, B0f[nt][0], cc, 0, 0, 0);
            cc = __builtin_amdgcn_mfma_f32_16x16x32_f16(a1, B0f[nt][1], cc, 0, 0, 0);
            acc[mt][nt] = cc;
        }
    }
    #pragma unroll
    for (int mt = 0; mt < 4; ++mt)
        #pragma unroll
        for (int nt = 0; nt < 4; ++nt) {
            int ch = nt * 16 + l15;
            #pragma unroll
            for (int r = 0; r < 4; ++r) {
                float v = fmaxf(acc[mt][nt][r] + bias0[nt], 0.0f);
                H[(mt * 16 + kg * 4 + r) * HS + ch] = (_Float16)v;
            }
        }

    // ---- layer 1 ----
    floatx4 acc2[4][4];
    #pragma unroll
    for (int mt = 0; mt < 4; ++mt) {
        const _Float16* hp = &H[(mt * 16 + l15) * HS];
        half8 a0 = *(const half8*)&hp[kg * 8];
        half8 a1 = *(const half8*)&hp[32 + kg * 8];
        #pragma unroll
        for (int nt = 0; nt < 4; ++nt) {
            floatx4 cc = {0.f, 0.f, 0.f, 0.f};
            cc = __builtin_amdgcn_mfma_f32_16x16x32_f16(a0, B1f[nt][0], cc, 0, 0, 0);
            cc = __builtin_amdgcn_mfma_f32_16x16x32_f16(a1, B1f[nt][1], cc, 0, 0, 0);
            acc2[mt][nt] = cc;
        }
    }

    // ---- layer 2 + 16-lane reduce ----
    float p[4][4];
    #pragma unroll
    for (int mt = 0; mt < 4; ++mt)
        #pragma unroll
        for (int r = 0; r < 4; ++r) p[mt][r] = 0.0f;
    #pragma unroll
    for (int mt = 0; mt < 4; ++mt)
        #pragma unroll
        for (int nt = 0; nt < 4; ++nt)
            #pragma unroll
            for (int r = 0; r < 4; ++r) {
                float v = fmaxf(acc2[mt][nt][r] + bias1[nt], 0.0f);
                p[mt][r] = fmaf(v, w2v[nt], p[mt][r]);
            }
    #pragma unroll
    for (int mt = 0; mt < 4; ++mt)
        #pragma unroll
        for (int r = 0; r < 4; ++r) {
            float s = p[mt][r];
            s += __shfl_xor(s, 1);
            s += __shfl_xor(s, 2);
            s += __shfl_xor(s, 4);
            s += __shfl_xor(s, 8);
            p[mt][r] = s;
        }

    float* HF = (float*)H;
    float ob = b2[0];
    if (l15 == 0) {
        #pragma unroll
        for (int mt = 0; mt < 4; ++mt)
            #pragma unroll
            for (int r = 0; r < 4; ++r)
                HF[mt * 16 + kg * 4 + r] = p[mt][r] + ob;
    }
    long pos = wbase + lane;
    if (pos < N) out[nidx[pos]] = HF[lane];
}

// ---------------------------------------------------------------------------
// Fallback: monolithic fused kernel reading raw f32 grids (no ws needed)
// ---------------------------------------------------------------------------
__global__ __launch_bounds__(256)
void fused_fallback_kernel(const float* __restrict__ x,
                           const float* __restrict__ scales,
                           const float* __restrict__ trans,
                           const float* __restrict__ fg,
                           const float* __restrict__ W0, const float* __restrict__ b0,
                           const float* __restrict__ W1, const float* __restrict__ b1,
                           const float* __restrict__ W2, const float* __restrict__ b2,
                           float* __restrict__ out, int N)
{
    __shared__ float sW0[NPL*NPL], sW1[NPL*NPL], sW2[NPL], sb0[NPL], sb1[NPL];
    __shared__ float sA[NG*3], sB[NG*3];
    const int tid = threadIdx.x;
    for (int i = tid; i < NPL*NPL; i += 256) { sW0[i] = W0[i]; sW1[i] = W1[i]; }
    if (tid < NPL) { sW2[tid] = W2[tid]; sb0[tid] = b0[tid]; sb1[tid] = b1[tid]; }
    if (tid < NG*3) {
        const float k = (1.0f / 1.48f) * 31.5f;
        sA[tid] = scales[tid] * k;
        sB[tid] = trans[tid] * k + 31.5f;
    }
    __syncthreads();
    int n = blockIdx.x * 256 + tid;
    if (n >= N) return;
    float px = x[3*n], py = x[3*n+1], pz = x[3*n+2];
    float feat[2*NG];
    #pragma unroll
    for (int g = 0; g < NG; ++g) {
        float fx = fmaf(px, sA[3*g+0], sB[3*g+0]);
        float fy = fmaf(py, sA[3*g+1], sB[3*g+1]);
        float fz = fmaf(pz, sA[3*g+2], sB[3*g+2]);
        float c0 = 0.f, c1 = 0.f;
        if (fx > -1.f && fx < 64.f && fy > -1.f && fy < 64.f && fz > -1.f && fz < 64.f) {
            float flx = floorf(fx), fly = floorf(fy), flz = floorf(fz);
            int x0 = (int)flx, y0 = (int)fly, z0 = (int)flz;
            float wx = fx-flx, wy = fy-fly, wz = fz-flz;
            float wxa[2], wya[2], wza[2]; int xia[2], yia[2], zia[2];
            wxa[0] = (x0 >= 0  && x0   < DG) ? (1.f-wx) : 0.f;
            wxa[1] = (x0 >= -1 && x0+1 < DG) ? wx : 0.f;
            wya[0] = (y0 >= 0  && y0   < DG) ? (1.f-wy) : 0.f;
            wya[1] = (y0 >= -1 && y0+1 < DG) ? wy : 0.f;
            wza[0] = (z0 >= 0  && z0   < DG) ? (1.f-wz) : 0.f;
            wza[1] = (z0 >= -1 && z0+1 < DG) ? wz : 0.f;
            xia[0] = min(max(x0,0),DG-1); xia[1] = min(max(x0+1,0),DG-1);
            yia[0] = min(max(y0,0),DG-1); yia[1] = min(max(y0+1,0),DG-1);
            zia[0] = min(max(z0,0),DG-1); zia[1] = min(max(z0+1,0),DG-1);
            const float* fr = fg + ((size_t)g << 19);
            #pragma unroll
            for (int dz = 0; dz < 2; ++dz)
                #pragma unroll
                for (int dy = 0; dy < 2; ++dy) {
                    int rowoff = (zia[dz] << 12) + (yia[dy] << 6);
                    float wyz = wya[dy] * wza[dz];
                    #pragma unroll
                    for (int dx = 0; dx < 2; ++dx) {
                        float w = wxa[dx] * wyz;
                        c0 = fmaf(w, fr[rowoff + xia[dx]], c0);
                        c1 = fmaf(w, fr[(1 << 18) + rowoff + xia[dx]], c1);
                    }
                }
        }
        feat[2*g] = c0; feat[2*g+1] = c1;
    }
    float h1[NPL];
    #pragma unroll
    for (int j = 0; j < NPL; j += 2) {
        float a0=0.f,a1=0.f,a2=0.f,a3=0.f;
        const float* r0 = &sW0[j*NPL]; const float* r1 = &sW0[(j+1)*NPL];
        #pragma unroll
        for (int k = 0; k < NPL; k += 2) {
            a0 = fmaf(feat[k],r0[k],a0); a1 = fmaf(feat[k+1],r0[k+1],a1);
            a2 = fmaf(feat[k],r1[k],a2); a3 = fmaf(feat[k+1],r1[k+1],a3);
        }
        h1[j] = fmaxf((a0+a1)+sb0[j],0.f); h1[j+1] = fmaxf((a2+a3)+sb0[j+1],0.f);
    }
    #pragma unroll
    for (int j = 0; j < NPL; j += 2) {
        float a0=0.f,a1=0.f,a2=0.f,a3=0.f;
        const float* r0 = &sW1[j*NPL]; const float* r1 = &sW1[(j+1)*NPL];
        #pragma unroll
        for (int k = 0; k < NPL; k += 2) {
            a0 = fmaf(h1[k],r0[k],a0); a1 = fmaf(h1[k+1],r0[k+1],a1);
            a2 = fmaf(h1[k],r1[k],a2); a3 = fmaf(h1[k+1],r1[k+1],a3);
        }
        feat[j] = fmaxf((a0+a1)+sb1[j],0.f); feat[j+1] = fmaxf((a2+a3)+sb1[j+1],0.f);
    }
    float a0 = 0.f, a1 = 0.f;
    #pragma unroll
    for (int k = 0; k < NPL; k += 2) { a0 = fmaf(feat[k],sW2[k],a0); a1 = fmaf(feat[k+1],sW2[k+1],a1); }
    out[n] = (a0+a1) + b2[0];
}

// ---------------------------------------------------------------------------
extern "C" void kernel_launch(void* const* d_in, const int* in_sizes, int n_in,
                              void* d_out, int out_size, void* d_ws, size_t ws_size,
                              hipStream_t stream) {
    const float* x  = (const float*)d_in[0];
    const float* gs = (const float*)d_in[1];
    const float* gt = (const float*)d_in[2];
    const float* fg = (const float*)d_in[3];
    const float* W0 = (const float*)d_in[4];
    const float* b0 = (const float*)d_in[5];
    const float* W1 = (const float*)d_in[6];
    const float* b1 = (const float*)d_in[7];
    const float* W2 = (const float*)d_in[8];
    const float* b2 = (const float*)d_in[9];
    float* out = (float*)d_out;

    const int N = out_size;

    const size_t pg_bytes    = (size_t)NG * (1 << 18) * 4;                // 33.5 MB
    const size_t fb_bytes    = (size_t)N * NG * 4;                        // 67.1 MB
    const size_t sort_bytes  = (size_t)N * sizeof(float4);                // 8 MB
    const size_t nidx_bytes  = (size_t)N * sizeof(int);                   // 2 MB
    const size_t cs_bytes    = ((NC2 + 1 + 15) & ~15) * sizeof(int);
    const size_t hist_bytes  = (size_t)NC2 * HPAD * sizeof(int);          // 256 KB
    const size_t pairs_bytes = (size_t)NPAIR * 4;                         // 64 KB
    const size_t ctr_bytes   = 64;
    const size_t need_full   = pg_bytes + fb_bytes + sort_bytes + nidx_bytes
                             + cs_bytes + 2 * hist_bytes + pairs_bytes + ctr_bytes;

    if (ws_size >= need_full) {
        char* w = (char*)d_ws;
        unsigned* pg        = (unsigned*)w;  w += pg_bytes;
        unsigned* fb        = (unsigned*)w;  w += fb_bytes;
        float4*   sorted    = (float4*)w;    w += sort_bytes;
        int*      nidx      = (int*)w;       w += nidx_bytes;
        int*      cellstart = (int*)w;       w += cs_bytes;
        int*      ghist     = (int*)w;       w += hist_bytes;
        int*      gcur      = (int*)w;       w += hist_bytes;
        unsigned* pairs     = (unsigned*)w;  w += pairs_bytes;
        int*      counters  = (int*)w;

        int total4   = NG << 16;             // 2M uint4
        int nPackB   = total4 / 1024;        // 2048 blocks, 4 uint4/thread
        int nHist    = (N + 2047) / 2048;    // 256
        int nSpecial = nHist + 1;            // + classify
        int nblkS    = (N + BS - 1) / BS;    // 1024

        hipMemsetAsync(ghist, 0, hist_bytes, stream);
        prelude4_kernel<<<nPackB + nSpecial, 256, 0, stream>>>(
            (const float4*)fg, (uint4*)pg, nHist, x, N, ghist,
            gs, gt, pairs, counters);
        scan_kernel<<<1, 1024, 0, stream>>>(ghist, gcur, cellstart);
        scatter_kernel<<<nblkS, BS, 0, stream>>>(x, N, gcur, sorted, nidx);
        gather2_kernel<<<NPAIR, BS, 0, stream>>>(
            sorted, cellstart, pairs, counters, gs, gt, pg, fb, N);
        mlp_kernel<<<(N + MBS - 1) / MBS, MBS, 0, stream>>>(
            fb, nidx, W0, b0, W1, b1, W2, b2, out, N);
    } else {
        fused_fallback_kernel<<<(N + 255) / 256, 256, 0, stream>>>(
            x, gs, gt, fg, W0, b0, W1, b1, W2, b2, out, N);
    }
}

// Round 18
// 186.486 us; speedup vs baseline: 1.0349x; 1.0349x over previous
//
#include <hip/hip_runtime.h>
#include <hip/hip_fp16.h>

#define NG    32
#define DG    64
#define NPL   64
#define CPD2  16               // sort granularity (fine cells)
#define NC2   4096             // 16^3 sort bins
#define NCELL 512              // gather cells (8^3)
#define NPAIR (NCELL * NG)     // 16384 (cell,grid) pairs
#define HPAD  16               // ints per padded counter (64B line)
#define BS    512
#define TV    4096             // 16^3 voxels per tile
#define HS    72               // mlp sH row stride (f16): 144B = 16B-aligned rows

// tile bank swizzle: XOR z-bits into bank bits; same on write and read.
#define SWZ(i) ((i) ^ (((i) >> 6) & 28))

typedef _Float16 half8 __attribute__((ext_vector_type(8)));
typedef float    floatx4 __attribute__((ext_vector_type(4)));

// ---------------------------------------------------------------------------
// Morton helpers
// ---------------------------------------------------------------------------
__device__ __forceinline__ int morton16(int cx, int cy, int cz) {
    int m = 0;
    #pragma unroll
    for (int b = 0; b < 4; ++b)
        m |= (((cx >> b) & 1) << (3 * b))
           | (((cy >> b) & 1) << (3 * b + 1))
           | (((cz >> b) & 1) << (3 * b + 2));
    return m;
}
__device__ __forceinline__ int cell_of(float px, float py, float pz) {
    int cx = min(max((int)((px + 1.0f) * (0.5f * CPD2)), 0), CPD2 - 1);
    int cy = min(max((int)((py + 1.0f) * (0.5f * CPD2)), 0), CPD2 - 1);
    int cz = min(max((int)((pz + 1.0f) * (0.5f * CPD2)), 0), CPD2 - 1);
    return morton16(cx, cy, cz);
}

// ---------------------------------------------------------------------------
// Pack (standalone, ZERO LDS): lane-interleaved, 4 uint4/thread, all 8
// input float4 loads issued before first use. 2048 blocks x 256 threads.
// ---------------------------------------------------------------------------
__global__ __launch_bounds__(256)
void pack_kernel(const float4* __restrict__ fga, uint4* __restrict__ pg) {
    const int tid   = threadIdx.x;
    const int base4 = blockIdx.x * 1024;
    int    idx[4];
    float4 a[4], b[4];
    #pragma unroll
    for (int k = 0; k < 4; ++k) {
        idx[k] = base4 + k * 256 + tid;
        int g  = idx[k] >> 16;
        int v4 = idx[k] & 65535;
        const float4* p0 = fga + ((size_t)g << 17) + v4;   // ch0 plane
        a[k] = p0[0];
        b[k] = p0[1 << 16];                                // ch1 plane
    }
    #pragma unroll
    for (int k = 0; k < 4; ++k) {
        uint4 o;
        __half2 h;
        h = __floats2half2_rn(a[k].x, b[k].x); o.x = *(unsigned*)&h;
        h = __floats2half2_rn(a[k].y, b[k].y); o.y = *(unsigned*)&h;
        h = __floats2half2_rn(a[k].z, b[k].z); o.z = *(unsigned*)&h;
        h = __floats2half2_rn(a[k].w, b[k].w); o.w = *(unsigned*)&h;
        pg[idx[k]] = o;
    }
}

// ---------------------------------------------------------------------------
// histcls: blocks [0,nHist) histogram 2048 points each (ghist pre-zeroed);
// block nHist classifies all 16384 (cell,grid) pairs.
// ---------------------------------------------------------------------------
__global__ __launch_bounds__(256)
void histcls_kernel(const float* __restrict__ x, int N, int nHist,
                    int* __restrict__ ghist,
                    const float* __restrict__ scales,
                    const float* __restrict__ trans,
                    unsigned* __restrict__ pairs, int* __restrict__ counters)
{
    __shared__ int lh[NC2];
    const int tid = threadIdx.x;
    const int bid = blockIdx.x;

    if (bid < nHist) {
        for (int i = tid; i < NC2; i += 256) lh[i] = 0;
        __syncthreads();
        int base = bid * 2048 + tid;
        #pragma unroll
        for (int s = 0; s < 8; ++s) {
            int n = base + s * 256;
            if (n < N) atomicAdd(&lh[cell_of(x[3*n], x[3*n+1], x[3*n+2])], 1);
        }
        __syncthreads();
        for (int i = tid; i < NC2; i += 256) {
            int c = lh[i];
            if (c) atomicAdd(&ghist[i * HPAD], c);
        }
        return;
    }

    // ---- classify block (lh[0..1] = head/tail) ----
    __shared__ float sA[NG * 3], sB[NG * 3];
    const int lane = tid & 63;
    if (tid == 0) { lh[0] = 0; lh[1] = NPAIR; }
    if (tid < NG * 3) {
        const float k = (1.0f / 1.48f) * 31.5f;
        sA[tid] = scales[tid] * k;
        sB[tid] = trans[tid] * k + 31.5f;
    }
    __syncthreads();

    for (int p = tid; p < NPAIR; p += 256) {
        int c = p >> 5, g = p & 31;
        int cx = (c & 1)        | (((c >> 3) & 1) << 1) | (((c >> 6) & 1) << 2);
        int cy = ((c >> 1) & 1) | (((c >> 4) & 1) << 1) | (((c >> 7) & 1) << 2);
        int cz = ((c >> 2) & 1) | (((c >> 5) & 1) << 1) | (((c >> 8) & 1) << 2);
        bool skip = false, fast = true;
        #pragma unroll
        for (int d = 0; d < 3; ++d) {
            float A = sA[3 * g + d], B = sB[3 * g + d];
            int  cc = (d == 0) ? cx : ((d == 1) ? cy : cz);
            float lo = fmaf((float)cc, 0.25f, -1.0f) - 1e-4f;
            float hi = lo + 0.25f + 2e-4f;
            float fmn = fmaf(lo, A, B);       // A > 0 (scales > 0)
            float fmx = fmaf(hi, A, B);
            skip = skip || (fmx <= -1.0f) || (fmn >= 64.0f);
            fast = fast && (fmn >= 0.0f) && (fmx <= 62.9f);
        }
        unsigned code = ((unsigned)c << 6) | ((unsigned)g << 1) | (fast ? 1u : 0u);

        unsigned long long mAct = __ballot(!skip);
        int cntA = __popcll(mAct);
        int bA = 0, bS = 0;
        if (lane == 0) {
            bA = atomicAdd(&lh[0], cntA);
            bS = atomicAdd(&lh[1], -(64 - cntA));
        }
        bA = __shfl(bA, 0); bS = __shfl(bS, 0);
        unsigned long long below = (1ull << lane) - 1ull;
        if (!skip) pairs[bA + __popcll(mAct & below)] = code;
        else       pairs[bS - 1 - __popcll(~mAct & below)] = code;
    }
    __syncthreads();
    if (tid == 0) counters[0] = lh[0];
}

// ---------------------------------------------------------------------------
// Scan (1 block, 1024 threads)
// ---------------------------------------------------------------------------
__global__ __launch_bounds__(1024)
void scan_kernel(const int* __restrict__ ghist, int* __restrict__ gcursor,
                 int* __restrict__ cellstart) {
    __shared__ int tsum[1024];
    int t = threadIdx.x;
    int v0 = ghist[(t * 4 + 0) * HPAD];
    int v1 = ghist[(t * 4 + 1) * HPAD];
    int v2 = ghist[(t * 4 + 2) * HPAD];
    int v3 = ghist[(t * 4 + 3) * HPAD];
    tsum[t] = v0 + v1 + v2 + v3;
    __syncthreads();
    #pragma unroll
    for (int off = 1; off < 1024; off <<= 1) {
        int u = (t >= off) ? tsum[t - off] : 0;
        __syncthreads();
        tsum[t] += u;
        __syncthreads();
    }
    int base = (t == 0) ? 0 : tsum[t - 1];
    gcursor[(t*4+0)*HPAD] = base; cellstart[t*4+0] = base; base += v0;
    gcursor[(t*4+1)*HPAD] = base; cellstart[t*4+1] = base; base += v1;
    gcursor[(t*4+2)*HPAD] = base; cellstart[t*4+2] = base; base += v2;
    gcursor[(t*4+3)*HPAD] = base; cellstart[t*4+3] = base;
    if (t == 1023) cellstart[NC2] = tsum[1023];
}

__global__ __launch_bounds__(BS)
void scatter_kernel(const float* __restrict__ x, int N,
                    int* __restrict__ gcursor, float4* __restrict__ sorted,
                    int* __restrict__ nidx) {
    __shared__ int cnt[NC2];
    __shared__ int base[NC2];
    int tid = threadIdx.x;
    for (int i = tid; i < NC2; i += BS) cnt[i] = 0;
    __syncthreads();
    int n = blockIdx.x * BS + tid;
    float px = 0.f, py = 0.f, pz = 0.f;
    int c = 0, r = 0;
    bool act = (n < N);
    if (act) {
        px = x[3*n]; py = x[3*n+1]; pz = x[3*n+2];
        c = cell_of(px, py, pz);
        r = atomicAdd(&cnt[c], 1);
    }
    __syncthreads();
    for (int i = tid; i < NC2; i += BS) {
        int cc = cnt[i];
        base[i] = cc ? atomicAdd(&gcursor[i * HPAD], cc) : 0;
    }
    __syncthreads();
    if (act) {
        int pos = base[c] + r;
        sorted[pos] = make_float4(px, py, pz, 0.0f);
        nidx[pos]   = n;
    }
}

// ---------------------------------------------------------------------------
__device__ __forceinline__ float2 h2_to_f2(unsigned u) {
    __half2 h = *reinterpret_cast<__half2*>(&u);
    return __half22float2(h);
}

template<bool FAST>
__device__ __forceinline__ unsigned sample_tile(
    const unsigned* __restrict__ tl,
    float px, float py, float pz,
    float A0, float A1, float A2, float B0, float B1, float B2,
    int ox, int oy, int oz)
{
    float fx = fmaf(px, A0, B0);
    float fy = fmaf(py, A1, B1);
    float fz = fmaf(pz, A2, B2);
    float flx = floorf(fx), fly = floorf(fy), flz = floorf(fz);
    int x0 = (int)flx, y0 = (int)fly, z0 = (int)flz;
    float wx = fx - flx, wy = fy - fly, wz = fz - flz;

    float wxa0, wxa1, wya0, wya1, wza0, wza1;
    int ix0, ix1, iy0, iy1, iz0, iz1;
    if (FAST) {
        wxa0 = 1.0f - wx; wxa1 = wx;
        wya0 = 1.0f - wy; wya1 = wy;
        wza0 = 1.0f - wz; wza1 = wz;
        ix0 = x0 - ox;            ix1 = ix0 + 1;
        iy0 = (y0 - oy) << 4;     iy1 = iy0 + 16;
        iz0 = (z0 - oz) << 8;     iz1 = iz0 + 256;
    } else {
        wxa0 = (x0 >= 0  && x0     < DG) ? (1.0f - wx) : 0.0f;
        wxa1 = (x0 >= -1 && x0 + 1 < DG) ? wx          : 0.0f;
        wya0 = (y0 >= 0  && y0     < DG) ? (1.0f - wy) : 0.0f;
        wya1 = (y0 >= -1 && y0 + 1 < DG) ? wy          : 0.0f;
        wza0 = (z0 >= 0  && z0     < DG) ? (1.0f - wz) : 0.0f;
        wza1 = (z0 >= -1 && z0 + 1 < DG) ? wz          : 0.0f;
        ix0 = min(max(x0     - ox, 0), 15);
        ix1 = min(max(x0 + 1 - ox, 0), 15);
        iy0 = (min(max(y0     - oy, 0), 15)) << 4;
        iy1 = (min(max(y0 + 1 - oy, 0), 15)) << 4;
        iz0 = (min(max(z0     - oz, 0), 15)) << 8;
        iz1 = (min(max(z0 + 1 - oz, 0), 15)) << 8;
    }
    const int m0 = (iz0 >> 6) & 28;
    const int m1 = (iz1 >> 6) & 28;

    float w00 = wya0 * wza0, w10 = wya1 * wza0;
    float w01 = wya0 * wza1, w11 = wya1 * wza1;

    float c0 = 0.0f, c1 = 0.0f;
    float2 v;
    v = h2_to_f2(tl[(iz0+iy0+ix0)^m0]); c0 = fmaf(wxa0*w00, v.x, c0); c1 = fmaf(wxa0*w00, v.y, c1);
    v = h2_to_f2(tl[(iz0+iy0+ix1)^m0]); c0 = fmaf(wxa1*w00, v.x, c0); c1 = fmaf(wxa1*w00, v.y, c1);
    v = h2_to_f2(tl[(iz0+iy1+ix0)^m0]); c0 = fmaf(wxa0*w10, v.x, c0); c1 = fmaf(wxa0*w10, v.y, c1);
    v = h2_to_f2(tl[(iz0+iy1+ix1)^m0]); c0 = fmaf(wxa1*w10, v.x, c0); c1 = fmaf(wxa1*w10, v.y, c1);
    v = h2_to_f2(tl[(iz1+iy0+ix0)^m1]); c0 = fmaf(wxa0*w01, v.x, c0); c1 = fmaf(wxa0*w01, v.y, c1);
    v = h2_to_f2(tl[(iz1+iy0+ix1)^m1]); c0 = fmaf(wxa1*w01, v.x, c0); c1 = fmaf(wxa1*w01, v.y, c1);
    v = h2_to_f2(tl[(iz1+iy1+ix0)^m1]); c0 = fmaf(wxa0*w11, v.x, c0); c1 = fmaf(wxa0*w11, v.y, c1);
    v = h2_to_f2(tl[(iz1+iy1+ix1)^m1]); c0 = fmaf(wxa1*w11, v.x, c0); c1 = fmaf(wxa1*w11, v.y, c1);

    __half2 hv = __floats2half2_rn(c0, c1);
    return *reinterpret_cast<unsigned*>(&hv);
}

// ---------------------------------------------------------------------------
// Gather: one 512-thread block per (cell,grid) pair; staged from PACKED grids.
// ---------------------------------------------------------------------------
__global__ __launch_bounds__(BS)
void gather2_kernel(const float4* __restrict__ sorted,
                    const int*   __restrict__ cs16,
                    const unsigned* __restrict__ pairs,
                    const int*   __restrict__ counters,
                    const float* __restrict__ scales,
                    const float* __restrict__ trans,
                    const unsigned* __restrict__ pg,
                    unsigned* __restrict__ fb, int N)
{
    __shared__ unsigned tile[TV];           // 16 KB

    const int tid = threadIdx.x;
    const int nA  = counters[0];
    unsigned pr   = pairs[blockIdx.x];
    const int c   = pr >> 6;
    const int g   = (pr >> 1) & 31;
    const bool fastp = pr & 1;

    int s0 = cs16[c * 8];
    int e  = cs16[c * 8 + 8];

    if ((int)blockIdx.x >= nA) {            // skipped pair: zero-fill
        for (int i = s0 + tid; i < e; i += BS) fb[(size_t)g * N + i] = 0u;
        return;
    }
    if (s0 >= e) return;

    int cx = (c & 1)        | (((c >> 3) & 1) << 1) | (((c >> 6) & 1) << 2);
    int cy = ((c >> 1) & 1) | (((c >> 4) & 1) << 1) | (((c >> 7) & 1) << 2);
    int cz = ((c >> 2) & 1) | (((c >> 5) & 1) << 1) | (((c >> 8) & 1) << 2);

    const float k = (1.0f / 1.48f) * 31.5f;
    float A0 = scales[3*g+0] * k, B0 = trans[3*g+0] * k + 31.5f;
    float A1 = scales[3*g+1] * k, B1 = trans[3*g+1] * k + 31.5f;
    float A2 = scales[3*g+2] * k, B2 = trans[3*g+2] * k + 31.5f;
    int ox = min(max((int)floorf(fmaf((float)cx * 0.25f - 1.0f, A0, B0)), 0), 48);
    int oy = min(max((int)floorf(fmaf((float)cy * 0.25f - 1.0f, A1, B1)), 0), 48);
    int oz = min(max((int)floorf(fmaf((float)cz * 0.25f - 1.0f, A2, B2)), 0), 48);

    float4 q0, q1, q2;
    int  i0 = s0 + tid, i1 = s0 + BS + tid, i2 = s0 + 2 * BS + tid;
    bool a0_ = (i0 < e), a1_ = (i1 < e), a2_ = (i2 < e);
    q0 = a0_ ? sorted[i0] : make_float4(0,0,0,0);
    q1 = a1_ ? sorted[i1] : make_float4(0,0,0,0);
    q2 = a2_ ? sorted[i2] : make_float4(0,0,0,0);

    const unsigned* gb = pg + ((size_t)g << 18);
    #pragma unroll
    for (int jj = 0; jj < 8; ++jj) {
        int v = tid + (jj << 9);
        tile[SWZ(v)] = gb[((oz + (v >> 8)) << 12) + ((oy + ((v >> 4) & 15)) << 6)
                          + ox + (v & 15)];
    }
    __syncthreads();

    unsigned* dst = fb + (size_t)g * N;
    if (fastp) {
        if (a0_) dst[i0] = sample_tile<true >(tile, q0.x,q0.y,q0.z, A0,A1,A2,B0,B1,B2, ox,oy,oz);
        if (a1_) dst[i1] = sample_tile<true >(tile, q1.x,q1.y,q1.z, A0,A1,A2,B0,B1,B2, ox,oy,oz);
        if (a2_) dst[i2] = sample_tile<true >(tile, q2.x,q2.y,q2.z, A0,A1,A2,B0,B1,B2, ox,oy,oz);
    } else {
        if (a0_) dst[i0] = sample_tile<false>(tile, q0.x,q0.y,q0.z, A0,A1,A2,B0,B1,B2, ox,oy,oz);
        if (a1_) dst[i1] = sample_tile<false>(tile, q1.x,q1.y,q1.z, A0,A1,A2,B0,B1,B2, ox,oy,oz);
        if (a2_) dst[i2] = sample_tile<false>(tile, q2.x,q2.y,q2.z, A0,A1,A2,B0,B1,B2, ox,oy,oz);
    }
}

// ---------------------------------------------------------------------------
// MFMA MLP with LDS union (r16): weight staging region reused as H bounce.
// ---------------------------------------------------------------------------
#define MBS 256
__global__ __launch_bounds__(MBS, 3)
void mlp_kernel(const unsigned* __restrict__ fb,
                const int* __restrict__ nidx,
                const float* __restrict__ W0, const float* __restrict__ b0,
                const float* __restrict__ W1, const float* __restrict__ b1,
                const float* __restrict__ W2, const float* __restrict__ b2,
                float* __restrict__ out, int N)
{
    __shared__ __align__(16) _Float16 smem[4 * NPL * HS];   // 36,864 B
    __shared__ float sb0f[NPL], sb1f[NPL], sW2f[NPL];

    int tid = threadIdx.x;
    _Float16* sW0h = smem;
    _Float16* sW1h = smem + NPL * NPL;
    for (int i = tid; i < NPL * NPL; i += MBS) {
        sW0h[i] = (_Float16)W0[i];
        sW1h[i] = (_Float16)W1[i];
    }
    if (tid < NPL) { sb0f[tid] = b0[tid]; sb1f[tid] = b1[tid]; sW2f[tid] = W2[tid]; }
    __syncthreads();

    const int wave = tid >> 6;
    const int lane = tid & 63;
    const int l15  = lane & 15;
    const int kg   = lane >> 4;
    const long wbase = (long)blockIdx.x * MBS + wave * 64;
    const bool active = (wbase < N);

    half8 B0f[4][2], B1f[4][2];
    float bias0[4], bias1[4], w2v[4];
    #pragma unroll
    for (int nt = 0; nt < 4; ++nt) {
        int ch = nt * 16 + l15;
        #pragma unroll
        for (int kh = 0; kh < 2; ++kh) {
            int k = kh * 32 + kg * 8;
            B0f[nt][kh] = *(const half8*)&sW0h[ch * NPL + k];
            B1f[nt][kh] = *(const half8*)&sW1h[ch * NPL + k];
        }
        bias0[nt] = sb0f[ch];
        bias1[nt] = sb1f[ch];
        w2v[nt]   = sW2f[ch];
    }
    __syncthreads();            // weights read; smem region reusable
    if (!active) return;

    _Float16* H = &smem[wave * NPL * HS];

    // ---- layer 0: A from 8 u32 planes ----
    floatx4 acc[4][4];
    #pragma unroll
    for (int mt = 0; mt < 4; ++mt) {
        long pt = wbase + mt * 16 + l15;
        if (pt > N - 1) pt = N - 1;
        const unsigned* p0 = fb + (size_t)(4 * kg) * N + pt;
        const unsigned* p1 = fb + (size_t)(16 + 4 * kg) * N + pt;
        uint4 t0 = make_uint4(p0[0], p0[N], p0[2*(size_t)N], p0[3*(size_t)N]);
        uint4 t1 = make_uint4(p1[0], p1[N], p1[2*(size_t)N], p1[3*(size_t)N]);
        half8 a0 = *reinterpret_cast<half8*>(&t0);
        half8 a1 = *reinterpret_cast<half8*>(&t1);
        #pragma unroll
        for (int nt = 0; nt < 4; ++nt) {
            floatx4 cc = {0.f, 0.f, 0.f, 0.f};
            cc = __builtin_amdgcn_mfma_f32_16x16x32_f16(a0, B0f[nt][0], cc, 0, 0, 0);
            cc = __builtin_amdgcn_mfma_f32_16x16x32_f16(a1, B0f[nt][1], cc, 0, 0, 0);
            acc[mt][nt] = cc;
        }
    }
    #pragma unroll
    for (int mt = 0; mt < 4; ++mt)
        #pragma unroll
        for (int nt = 0; nt < 4; ++nt) {
            int ch = nt * 16 + l15;
            #pragma unroll
            for (int r = 0; r < 4; ++r) {
                float v = fmaxf(acc[mt][nt][r] + bias0[nt], 0.0f);
                H[(mt * 16 + kg * 4 + r) * HS + ch] = (_Float16)v;
            }
        }

    // ---- layer 1 ----
    floatx4 acc2[4][4];
    #pragma unroll
    for (int mt = 0; mt < 4; ++mt) {
        const _Float16* hp = &H[(mt * 16 + l15) * HS];
        half8 a0 = *(const half8*)&hp[kg * 8];
        half8 a1 = *(const half8*)&hp[32 + kg * 8];
        #pragma unroll
        for (int nt = 0; nt < 4; ++nt) {
            floatx4 cc = {0.f, 0.f, 0.f, 0.f};
            cc = __builtin_amdgcn_mfma_f32_16x16x32_f16(a0, B1f[nt][0], cc, 0, 0, 0);
            cc = __builtin_amdgcn_mfma_f32_16x16x32_f16(a1, B1f[nt][1], cc, 0, 0, 0);
            acc2[mt][nt] = cc;
        }
    }

    // ---- layer 2 + 16-lane reduce ----
    float p[4][4];
    #pragma unroll
    for (int mt = 0; mt < 4; ++mt)
        #pragma unroll
        for (int r = 0; r < 4; ++r) p[mt][r] = 0.0f;
    #pragma unroll
    for (int mt = 0; mt < 4; ++mt)
        #pragma unroll
        for (int nt = 0; nt < 4; ++nt)
            #pragma unroll
            for (int r = 0; r < 4; ++r) {
                float v = fmaxf(acc2[mt][nt][r] + bias1[nt], 0.0f);
                p[mt][r] = fmaf(v, w2v[nt], p[mt][r]);
            }
    #pragma unroll
    for (int mt = 0; mt < 4; ++mt)
        #pragma unroll
        for (int r = 0; r < 4; ++r) {
            float s = p[mt][r];
            s += __shfl_xor(s, 1);
            s += __shfl_xor(s, 2);
            s += __shfl_xor(s, 4);
            s += __shfl_xor(s, 8);
            p[mt][r] = s;
        }

    float* HF = (float*)H;
    float ob = b2[0];
    if (l15 == 0) {
        #pragma unroll
        for (int mt = 0; mt < 4; ++mt)
            #pragma unroll
            for (int r = 0; r < 4; ++r)
                HF[mt * 16 + kg * 4 + r] = p[mt][r] + ob;
    }
    long pos = wbase + lane;
    if (pos < N) out[nidx[pos]] = HF[lane];
}

// ---------------------------------------------------------------------------
// Fallback: monolithic fused kernel reading raw f32 grids (no ws needed)
// ---------------------------------------------------------------------------
__global__ __launch_bounds__(256)
void fused_fallback_kernel(const float* __restrict__ x,
                           const float* __restrict__ scales,
                           const float* __restrict__ trans,
                           const float* __restrict__ fg,
                           const float* __restrict__ W0, const float* __restrict__ b0,
                           const float* __restrict__ W1, const float* __restrict__ b1,
                           const float* __restrict__ W2, const float* __restrict__ b2,
                           float* __restrict__ out, int N)
{
    __shared__ float sW0[NPL*NPL], sW1[NPL*NPL], sW2[NPL], sb0[NPL], sb1[NPL];
    __shared__ float sA[NG*3], sB[NG*3];
    const int tid = threadIdx.x;
    for (int i = tid; i < NPL*NPL; i += 256) { sW0[i] = W0[i]; sW1[i] = W1[i]; }
    if (tid < NPL) { sW2[tid] = W2[tid]; sb0[tid] = b0[tid]; sb1[tid] = b1[tid]; }
    if (tid < NG*3) {
        const float k = (1.0f / 1.48f) * 31.5f;
        sA[tid] = scales[tid] * k;
        sB[tid] = trans[tid] * k + 31.5f;
    }
    __syncthreads();
    int n = blockIdx.x * 256 + tid;
    if (n >= N) return;
    float px = x[3*n], py = x[3*n+1], pz = x[3*n+2];
    float feat[2*NG];
    #pragma unroll
    for (int g = 0; g < NG; ++g) {
        float fx = fmaf(px, sA[3*g+0], sB[3*g+0]);
        float fy = fmaf(py, sA[3*g+1], sB[3*g+1]);
        float fz = fmaf(pz, sA[3*g+2], sB[3*g+2]);
        float c0 = 0.f, c1 = 0.f;
        if (fx > -1.f && fx < 64.f && fy > -1.f && fy < 64.f && fz > -1.f && fz < 64.f) {
            float flx = floorf(fx), fly = floorf(fy), flz = floorf(fz);
            int x0 = (int)flx, y0 = (int)fly, z0 = (int)flz;
            float wx = fx-flx, wy = fy-fly, wz = fz-flz;
            float wxa[2], wya[2], wza[2]; int xia[2], yia[2], zia[2];
            wxa[0] = (x0 >= 0  && x0   < DG) ? (1.f-wx) : 0.f;
            wxa[1] = (x0 >= -1 && x0+1 < DG) ? wx : 0.f;
            wya[0] = (y0 >= 0  && y0   < DG) ? (1.f-wy) : 0.f;
            wya[1] = (y0 >= -1 && y0+1 < DG) ? wy : 0.f;
            wza[0] = (z0 >= 0  && z0   < DG) ? (1.f-wz) : 0.f;
            wza[1] = (z0 >= -1 && z0+1 < DG) ? wz : 0.f;
            xia[0] = min(max(x0,0),DG-1); xia[1] = min(max(x0+1,0),DG-1);
            yia[0] = min(max(y0,0),DG-1); yia[1] = min(max(y0+1,0),DG-1);
            zia[0] = min(max(z0,0),DG-1); zia[1] = min(max(z0+1,0),DG-1);
            const float* fr = fg + ((size_t)g << 19);
            #pragma unroll
            for (int dz = 0; dz < 2; ++dz)
                #pragma unroll
                for (int dy = 0; dy < 2; ++dy) {
                    int rowoff = (zia[dz] << 12) + (yia[dy] << 6);
                    float wyz = wya[dy] * wza[dz];
                    #pragma unroll
                    for (int dx = 0; dx < 2; ++dx) {
                        float w = wxa[dx] * wyz;
                        c0 = fmaf(w, fr[rowoff + xia[dx]], c0);
                        c1 = fmaf(w, fr[(1 << 18) + rowoff + xia[dx]], c1);
                    }
                }
        }
        feat[2*g] = c0; feat[2*g+1] = c1;
    }
    float h1[NPL];
    #pragma unroll
    for (int j = 0; j < NPL; j += 2) {
        float a0=0.f,a1=0.f,a2=0.f,a3=0.f;
        const float* r0 = &sW0[j*NPL]; const float* r1 = &sW0[(j+1)*NPL];
        #pragma unroll
        for (int k = 0; k < NPL; k += 2) {
            a0 = fmaf(feat[k],r0[k],a0); a1 = fmaf(feat[k+1],r0[k+1],a1);
            a2 = fmaf(feat[k],r1[k],a2); a3 = fmaf(feat[k+1],r1[k+1],a3);
        }
        h1[j] = fmaxf((a0+a1)+sb0[j],0.f); h1[j+1] = fmaxf((a2+a3)+sb0[j+1],0.f);
    }
    #pragma unroll
    for (int j = 0; j < NPL; j += 2) {
        float a0=0.f,a1=0.f,a2=0.f,a3=0.f;
        const float* r0 = &sW1[j*NPL]; const float* r1 = &sW1[(j+1)*NPL];
        #pragma unroll
        for (int k = 0; k < NPL; k += 2) {
            a0 = fmaf(h1[k],r0[k],a0); a1 = fmaf(h1[k+1],r0[k+1],a1);
            a2 = fmaf(h1[k],r1[k],a2); a3 = fmaf(h1[k+1],r1[k+1],a3);
        }
        feat[j] = fmaxf((a0+a1)+sb1[j],0.f); feat[j+1] = fmaxf((a2+a3)+sb1[j+1],0.f);
    }
    float a0 = 0.f, a1 = 0.f;
    #pragma unroll
    for (int k = 0; k < NPL; k += 2) { a0 = fmaf(feat[k],sW2[k],a0); a1 = fmaf(feat[k+1],sW2[k+1],a1); }
    out[n] = (a0+a1) + b2[0];
}

// ---------------------------------------------------------------------------
extern "C" void kernel_launch(void* const* d_in, const int* in_sizes, int n_in,
                              void* d_out, int out_size, void* d_ws, size_t ws_size,
                              hipStream_t stream) {
    const float* x  = (const float*)d_in[0];
    const float* gs = (const float*)d_in[1];
    const float* gt = (const float*)d_in[2];
    const float* fg = (const float*)d_in[3];
    const float* W0 = (const float*)d_in[4];
    const float* b0 = (const float*)d_in[5];
    const float* W1 = (const float*)d_in[6];
    const float* b1 = (const float*)d_in[7];
    const float* W2 = (const float*)d_in[8];
    const float* b2 = (const float*)d_in[9];
    float* out = (float*)d_out;

    const int N = out_size;

    const size_t pg_bytes    = (size_t)NG * (1 << 18) * 4;                // 33.5 MB
    const size_t fb_bytes    = (size_t)N * NG * 4;                        // 67.1 MB
    const size_t sort_bytes  = (size_t)N * sizeof(float4);                // 8 MB
    const size_t nidx_bytes  = (size_t)N * sizeof(int);                   // 2 MB
    const size_t cs_bytes    = ((NC2 + 1 + 15) & ~15) * sizeof(int);
    const size_t hist_bytes  = (size_t)NC2 * HPAD * sizeof(int);          // 256 KB
    const size_t pairs_bytes = (size_t)NPAIR * 4;                         // 64 KB
    const size_t ctr_bytes   = 64;
    const size_t need_full   = pg_bytes + fb_bytes + sort_bytes + nidx_bytes
                             + cs_bytes + 2 * hist_bytes + pairs_bytes + ctr_bytes;

    if (ws_size >= need_full) {
        char* w = (char*)d_ws;
        unsigned* pg        = (unsigned*)w;  w += pg_bytes;
        unsigned* fb        = (unsigned*)w;  w += fb_bytes;
        float4*   sorted    = (float4*)w;    w += sort_bytes;
        int*      nidx      = (int*)w;       w += nidx_bytes;
        int*      cellstart = (int*)w;       w += cs_bytes;
        int*      ghist     = (int*)w;       w += hist_bytes;
        int*      gcur      = (int*)w;       w += hist_bytes;
        unsigned* pairs     = (unsigned*)w;  w += pairs_bytes;
        int*      counters  = (int*)w;

        int total4 = NG << 16;               // 2M uint4
        int nPackB = total4 / 1024;          // 2048 blocks, 4 uint4/thread
        int nHist  = (N + 2047) / 2048;      // 256
        int nblkS  = (N + BS - 1) / BS;      // 1024

        hipMemsetAsync(ghist, 0, hist_bytes, stream);
        pack_kernel<<<nPackB, 256, 0, stream>>>((const float4*)fg, (uint4*)pg);
        histcls_kernel<<<nHist + 1, 256, 0, stream>>>(
            x, N, nHist, ghist, gs, gt, pairs, counters);
        scan_kernel<<<1, 1024, 0, stream>>>(ghist, gcur, cellstart);
        scatter_kernel<<<nblkS, BS, 0, stream>>>(x, N, gcur, sorted, nidx);
        gather2_kernel<<<NPAIR, BS, 0, stream>>>(
            sorted, cellstart, pairs, counters, gs, gt, pg, fb, N);
        mlp_kernel<<<(N + MBS - 1) / MBS, MBS, 0, stream>>>(
            fb, nidx, W0, b0, W1, b1, W2, b2, out, N);
    } else {
        fused_fallback_kernel<<<(N + 255) / 256, 256, 0, stream>>>(
            x, gs, gt, fg, W0, b0, W1, b1, W2, b2, out, N);
    }
}

// Round 19
// 176.727 us; speedup vs baseline: 1.0921x; 1.0552x over previous
//
#include <hip/hip_runtime.h>
#include <hip/hip_fp16.h>

#define NG    32
#define DG    64
#define NPL   64
#define CPD2  16               // sort granularity (fine cells)
#define NC2   4096             // 16^3 sort bins
#define NCELL 512              // gather cells (8^3)
#define NPAIR (NCELL * NG)     // 16384 (cell,grid) pairs
#define HPAD  16               // ints per padded counter (64B line)
#define BS    512
#define TV    4096             // 16^3 voxels per tile
#define HS    72               // mlp sH row stride (f16): 144B = 16B-aligned rows

// tile bank swizzle: XOR z-bits into bank bits; same on write and read.
#define SWZ(i) ((i) ^ (((i) >> 6) & 28))

typedef _Float16 half8 __attribute__((ext_vector_type(8)));
typedef float    floatx4 __attribute__((ext_vector_type(4)));

// ---------------------------------------------------------------------------
// Morton helpers
// ---------------------------------------------------------------------------
__device__ __forceinline__ int morton16(int cx, int cy, int cz) {
    int m = 0;
    #pragma unroll
    for (int b = 0; b < 4; ++b)
        m |= (((cx >> b) & 1) << (3 * b))
           | (((cy >> b) & 1) << (3 * b + 1))
           | (((cz >> b) & 1) << (3 * b + 2));
    return m;
}
__device__ __forceinline__ int cell_of(float px, float py, float pz) {
    int cx = min(max((int)((px + 1.0f) * (0.5f * CPD2)), 0), CPD2 - 1);
    int cy = min(max((int)((py + 1.0f) * (0.5f * CPD2)), 0), CPD2 - 1);
    int cz = min(max((int)((pz + 1.0f) * (0.5f * CPD2)), 0), CPD2 - 1);
    return morton16(cx, cy, cz);
}

// ---------------------------------------------------------------------------
// Prelude3: fused pack + hist + classify (r15/r16 version).
// Pack blocks [0,nPackB): 4 uint4/thread, lane-interleaved (coalesced per
// instruction) with all 8 input float4 loads issued before first use.
// Hist blocks [nPackB, nPackB+nHist): 2048 points each (ghist pre-zeroed).
// Last block: classify 16384 (cell,grid) pairs.
// ---------------------------------------------------------------------------
__global__ __launch_bounds__(256)
void prelude3_kernel(const float4* __restrict__ fga, uint4* __restrict__ pg,
                     int nPackB, int nHist,
                     const float* __restrict__ x, int N,
                     int* __restrict__ ghist,
                     const float* __restrict__ scales,
                     const float* __restrict__ trans,
                     unsigned* __restrict__ pairs, int* __restrict__ counters)
{
    __shared__ int lh[NC2];                  // hist/classify branches only
    const int tid = threadIdx.x;
    const int bid = blockIdx.x;

    if (bid < nPackB) {
        // ---- pack: 1024 uint4 per block, lane-interleaved ----
        const int base4 = bid * 1024;
        int   idx[4];
        float4 a[4], b[4];
        #pragma unroll
        for (int k = 0; k < 4; ++k) {
            idx[k] = base4 + k * 256 + tid;
            int g  = idx[k] >> 16;
            int v4 = idx[k] & 65535;
            const float4* p0 = fga + ((size_t)g << 17) + v4;  // ch0 plane
            a[k] = p0[0];
            b[k] = p0[1 << 16];                               // ch1 plane
        }
        #pragma unroll
        for (int k = 0; k < 4; ++k) {
            uint4 o;
            __half2 h;
            h = __floats2half2_rn(a[k].x, b[k].x); o.x = *(unsigned*)&h;
            h = __floats2half2_rn(a[k].y, b[k].y); o.y = *(unsigned*)&h;
            h = __floats2half2_rn(a[k].z, b[k].z); o.z = *(unsigned*)&h;
            h = __floats2half2_rn(a[k].w, b[k].w); o.w = *(unsigned*)&h;
            pg[idx[k]] = o;
        }
        return;
    }

    if (bid < nPackB + nHist) {
        // ---- hist (2048 points per block) ----
        int hb = bid - nPackB;
        for (int i = tid; i < NC2; i += 256) lh[i] = 0;
        __syncthreads();
        int base = hb * 2048 + tid;
        #pragma unroll
        for (int s = 0; s < 8; ++s) {
            int n = base + s * 256;
            if (n < N) atomicAdd(&lh[cell_of(x[3*n], x[3*n+1], x[3*n+2])], 1);
        }
        __syncthreads();
        for (int i = tid; i < NC2; i += 256) {
            int c = lh[i];
            if (c) atomicAdd(&ghist[i * HPAD], c);
        }
        return;
    }

    // ---- classify block (lh[0..1] = head/tail) ----
    __shared__ float sA[NG * 3], sB[NG * 3];
    const int lane = tid & 63;
    if (tid == 0) { lh[0] = 0; lh[1] = NPAIR; }
    if (tid < NG * 3) {
        const float k = (1.0f / 1.48f) * 31.5f;
        sA[tid] = scales[tid] * k;
        sB[tid] = trans[tid] * k + 31.5f;
    }
    __syncthreads();

    for (int p = tid; p < NPAIR; p += 256) {
        int c = p >> 5, g = p & 31;
        int cx = (c & 1)        | (((c >> 3) & 1) << 1) | (((c >> 6) & 1) << 2);
        int cy = ((c >> 1) & 1) | (((c >> 4) & 1) << 1) | (((c >> 7) & 1) << 2);
        int cz = ((c >> 2) & 1) | (((c >> 5) & 1) << 1) | (((c >> 8) & 1) << 2);
        bool skip = false, fast = true;
        #pragma unroll
        for (int d = 0; d < 3; ++d) {
            float A = sA[3 * g + d], B = sB[3 * g + d];
            int  cc = (d == 0) ? cx : ((d == 1) ? cy : cz);
            float lo = fmaf((float)cc, 0.25f, -1.0f) - 1e-4f;
            float hi = lo + 0.25f + 2e-4f;
            float fmn = fmaf(lo, A, B);       // A > 0 (scales > 0)
            float fmx = fmaf(hi, A, B);
            skip = skip || (fmx <= -1.0f) || (fmn >= 64.0f);
            fast = fast && (fmn >= 0.0f) && (fmx <= 62.9f);
        }
        unsigned code = ((unsigned)c << 6) | ((unsigned)g << 1) | (fast ? 1u : 0u);

        unsigned long long mAct = __ballot(!skip);
        int cntA = __popcll(mAct);
        int bA = 0, bS = 0;
        if (lane == 0) {
            bA = atomicAdd(&lh[0], cntA);
            bS = atomicAdd(&lh[1], -(64 - cntA));
        }
        bA = __shfl(bA, 0); bS = __shfl(bS, 0);
        unsigned long long below = (1ull << lane) - 1ull;
        if (!skip) pairs[bA + __popcll(mAct & below)] = code;
        else       pairs[bS - 1 - __popcll(~mAct & below)] = code;
    }
    __syncthreads();
    if (tid == 0) counters[0] = lh[0];
}

// ---------------------------------------------------------------------------
// Scan (1 block, 1024 threads)
// ---------------------------------------------------------------------------
__global__ __launch_bounds__(1024)
void scan_kernel(const int* __restrict__ ghist, int* __restrict__ gcursor,
                 int* __restrict__ cellstart) {
    __shared__ int tsum[1024];
    int t = threadIdx.x;
    int v0 = ghist[(t * 4 + 0) * HPAD];
    int v1 = ghist[(t * 4 + 1) * HPAD];
    int v2 = ghist[(t * 4 + 2) * HPAD];
    int v3 = ghist[(t * 4 + 3) * HPAD];
    tsum[t] = v0 + v1 + v2 + v3;
    __syncthreads();
    #pragma unroll
    for (int off = 1; off < 1024; off <<= 1) {
        int u = (t >= off) ? tsum[t - off] : 0;
        __syncthreads();
        tsum[t] += u;
        __syncthreads();
    }
    int base = (t == 0) ? 0 : tsum[t - 1];
    gcursor[(t*4+0)*HPAD] = base; cellstart[t*4+0] = base; base += v0;
    gcursor[(t*4+1)*HPAD] = base; cellstart[t*4+1] = base; base += v1;
    gcursor[(t*4+2)*HPAD] = base; cellstart[t*4+2] = base; base += v2;
    gcursor[(t*4+3)*HPAD] = base; cellstart[t*4+3] = base;
    if (t == 1023) cellstart[NC2] = tsum[1023];
}

__global__ __launch_bounds__(BS)
void scatter_kernel(const float* __restrict__ x, int N,
                    int* __restrict__ gcursor, float4* __restrict__ sorted,
                    int* __restrict__ nidx) {
    __shared__ int cnt[NC2];
    __shared__ int base[NC2];
    int tid = threadIdx.x;
    for (int i = tid; i < NC2; i += BS) cnt[i] = 0;
    __syncthreads();
    int n = blockIdx.x * BS + tid;
    float px = 0.f, py = 0.f, pz = 0.f;
    int c = 0, r = 0;
    bool act = (n < N);
    if (act) {
        px = x[3*n]; py = x[3*n+1]; pz = x[3*n+2];
        c = cell_of(px, py, pz);
        r = atomicAdd(&cnt[c], 1);
    }
    __syncthreads();
    for (int i = tid; i < NC2; i += BS) {
        int cc = cnt[i];
        base[i] = cc ? atomicAdd(&gcursor[i * HPAD], cc) : 0;
    }
    __syncthreads();
    if (act) {
        int pos = base[c] + r;
        sorted[pos] = make_float4(px, py, pz, 0.0f);
        nidx[pos]   = n;
    }
}

// ---------------------------------------------------------------------------
__device__ __forceinline__ float2 h2_to_f2(unsigned u) {
    __half2 h = *reinterpret_cast<__half2*>(&u);
    return __half22float2(h);
}

template<bool FAST>
__device__ __forceinline__ unsigned sample_tile(
    const unsigned* __restrict__ tl,
    float px, float py, float pz,
    float A0, float A1, float A2, float B0, float B1, float B2,
    int ox, int oy, int oz)
{
    float fx = fmaf(px, A0, B0);
    float fy = fmaf(py, A1, B1);
    float fz = fmaf(pz, A2, B2);
    float flx = floorf(fx), fly = floorf(fy), flz = floorf(fz);
    int x0 = (int)flx, y0 = (int)fly, z0 = (int)flz;
    float wx = fx - flx, wy = fy - fly, wz = fz - flz;

    float wxa0, wxa1, wya0, wya1, wza0, wza1;
    int ix0, ix1, iy0, iy1, iz0, iz1;
    if (FAST) {
        wxa0 = 1.0f - wx; wxa1 = wx;
        wya0 = 1.0f - wy; wya1 = wy;
        wza0 = 1.0f - wz; wza1 = wz;
        ix0 = x0 - ox;            ix1 = ix0 + 1;
        iy0 = (y0 - oy) << 4;     iy1 = iy0 + 16;
        iz0 = (z0 - oz) << 8;     iz1 = iz0 + 256;
    } else {
        wxa0 = (x0 >= 0  && x0     < DG) ? (1.0f - wx) : 0.0f;
        wxa1 = (x0 >= -1 && x0 + 1 < DG) ? wx          : 0.0f;
        wya0 = (y0 >= 0  && y0     < DG) ? (1.0f - wy) : 0.0f;
        wya1 = (y0 >= -1 && y0 + 1 < DG) ? wy          : 0.0f;
        wza0 = (z0 >= 0  && z0     < DG) ? (1.0f - wz) : 0.0f;
        wza1 = (z0 >= -1 && z0 + 1 < DG) ? wz          : 0.0f;
        ix0 = min(max(x0     - ox, 0), 15);
        ix1 = min(max(x0 + 1 - ox, 0), 15);
        iy0 = (min(max(y0     - oy, 0), 15)) << 4;
        iy1 = (min(max(y0 + 1 - oy, 0), 15)) << 4;
        iz0 = (min(max(z0     - oz, 0), 15)) << 8;
        iz1 = (min(max(z0 + 1 - oz, 0), 15)) << 8;
    }
    const int m0 = (iz0 >> 6) & 28;
    const int m1 = (iz1 >> 6) & 28;

    float w00 = wya0 * wza0, w10 = wya1 * wza0;
    float w01 = wya0 * wza1, w11 = wya1 * wza1;

    float c0 = 0.0f, c1 = 0.0f;
    float2 v;
    v = h2_to_f2(tl[(iz0+iy0+ix0)^m0]); c0 = fmaf(wxa0*w00, v.x, c0); c1 = fmaf(wxa0*w00, v.y, c1);
    v = h2_to_f2(tl[(iz0+iy0+ix1)^m0]); c0 = fmaf(wxa1*w00, v.x, c0); c1 = fmaf(wxa1*w00, v.y, c1);
    v = h2_to_f2(tl[(iz0+iy1+ix0)^m0]); c0 = fmaf(wxa0*w10, v.x, c0); c1 = fmaf(wxa0*w10, v.y, c1);
    v = h2_to_f2(tl[(iz0+iy1+ix1)^m0]); c0 = fmaf(wxa1*w10, v.x, c0); c1 = fmaf(wxa1*w10, v.y, c1);
    v = h2_to_f2(tl[(iz1+iy0+ix0)^m1]); c0 = fmaf(wxa0*w01, v.x, c0); c1 = fmaf(wxa0*w01, v.y, c1);
    v = h2_to_f2(tl[(iz1+iy0+ix1)^m1]); c0 = fmaf(wxa1*w01, v.x, c0); c1 = fmaf(wxa1*w01, v.y, c1);
    v = h2_to_f2(tl[(iz1+iy1+ix0)^m1]); c0 = fmaf(wxa0*w11, v.x, c0); c1 = fmaf(wxa0*w11, v.y, c1);
    v = h2_to_f2(tl[(iz1+iy1+ix1)^m1]); c0 = fmaf(wxa1*w11, v.x, c0); c1 = fmaf(wxa1*w11, v.y, c1);

    __half2 hv = __floats2half2_rn(c0, c1);
    return *reinterpret_cast<unsigned*>(&hv);
}

// ---------------------------------------------------------------------------
// Gather: one 512-thread block per (cell,grid) pair; staged from PACKED grids.
// ---------------------------------------------------------------------------
__global__ __launch_bounds__(BS)
void gather2_kernel(const float4* __restrict__ sorted,
                    const int*   __restrict__ cs16,
                    const unsigned* __restrict__ pairs,
                    const int*   __restrict__ counters,
                    const float* __restrict__ scales,
                    const float* __restrict__ trans,
                    const unsigned* __restrict__ pg,
                    unsigned* __restrict__ fb, int N)
{
    __shared__ unsigned tile[TV];           // 16 KB

    const int tid = threadIdx.x;
    const int nA  = counters[0];
    unsigned pr   = pairs[blockIdx.x];
    const int c   = pr >> 6;
    const int g   = (pr >> 1) & 31;
    const bool fastp = pr & 1;

    int s0 = cs16[c * 8];
    int e  = cs16[c * 8 + 8];

    if ((int)blockIdx.x >= nA) {            // skipped pair: zero-fill
        for (int i = s0 + tid; i < e; i += BS) fb[(size_t)g * N + i] = 0u;
        return;
    }
    if (s0 >= e) return;

    int cx = (c & 1)        | (((c >> 3) & 1) << 1) | (((c >> 6) & 1) << 2);
    int cy = ((c >> 1) & 1) | (((c >> 4) & 1) << 1) | (((c >> 7) & 1) << 2);
    int cz = ((c >> 2) & 1) | (((c >> 5) & 1) << 1) | (((c >> 8) & 1) << 2);

    const float k = (1.0f / 1.48f) * 31.5f;
    float A0 = scales[3*g+0] * k, B0 = trans[3*g+0] * k + 31.5f;
    float A1 = scales[3*g+1] * k, B1 = trans[3*g+1] * k + 31.5f;
    float A2 = scales[3*g+2] * k, B2 = trans[3*g+2] * k + 31.5f;
    int ox = min(max((int)floorf(fmaf((float)cx * 0.25f - 1.0f, A0, B0)), 0), 48);
    int oy = min(max((int)floorf(fmaf((float)cy * 0.25f - 1.0f, A1, B1)), 0), 48);
    int oz = min(max((int)floorf(fmaf((float)cz * 0.25f - 1.0f, A2, B2)), 0), 48);

    float4 q0, q1, q2;
    int  i0 = s0 + tid, i1 = s0 + BS + tid, i2 = s0 + 2 * BS + tid;
    bool a0_ = (i0 < e), a1_ = (i1 < e), a2_ = (i2 < e);
    q0 = a0_ ? sorted[i0] : make_float4(0,0,0,0);
    q1 = a1_ ? sorted[i1] : make_float4(0,0,0,0);
    q2 = a2_ ? sorted[i2] : make_float4(0,0,0,0);

    const unsigned* gb = pg + ((size_t)g << 18);
    #pragma unroll
    for (int jj = 0; jj < 8; ++jj) {
        int v = tid + (jj << 9);
        tile[SWZ(v)] = gb[((oz + (v >> 8)) << 12) + ((oy + ((v >> 4) & 15)) << 6)
                          + ox + (v & 15)];
    }
    __syncthreads();

    unsigned* dst = fb + (size_t)g * N;
    if (fastp) {
        if (a0_) dst[i0] = sample_tile<true >(tile, q0.x,q0.y,q0.z, A0,A1,A2,B0,B1,B2, ox,oy,oz);
        if (a1_) dst[i1] = sample_tile<true >(tile, q1.x,q1.y,q1.z, A0,A1,A2,B0,B1,B2, ox,oy,oz);
        if (a2_) dst[i2] = sample_tile<true >(tile, q2.x,q2.y,q2.z, A0,A1,A2,B0,B1,B2, ox,oy,oz);
    } else {
        if (a0_) dst[i0] = sample_tile<false>(tile, q0.x,q0.y,q0.z, A0,A1,A2,B0,B1,B2, ox,oy,oz);
        if (a1_) dst[i1] = sample_tile<false>(tile, q1.x,q1.y,q1.z, A0,A1,A2,B0,B1,B2, ox,oy,oz);
        if (a2_) dst[i2] = sample_tile<false>(tile, q2.x,q2.y,q2.z, A0,A1,A2,B0,B1,B2, ox,oy,oz);
    }
}

// ---------------------------------------------------------------------------
// MFMA MLP with LDS union (r16): weight staging region reused as H bounce.
// ---------------------------------------------------------------------------
#define MBS 256
__global__ __launch_bounds__(MBS, 3)
void mlp_kernel(const unsigned* __restrict__ fb,
                const int* __restrict__ nidx,
                const float* __restrict__ W0, const float* __restrict__ b0,
                const float* __restrict__ W1, const float* __restrict__ b1,
                const float* __restrict__ W2, const float* __restrict__ b2,
                float* __restrict__ out, int N)
{
    __shared__ __align__(16) _Float16 smem[4 * NPL * HS];   // 36,864 B
    __shared__ float sb0f[NPL], sb1f[NPL], sW2f[NPL];

    int tid = threadIdx.x;
    _Float16* sW0h = smem;
    _Float16* sW1h = smem + NPL * NPL;
    for (int i = tid; i < NPL * NPL; i += MBS) {
        sW0h[i] = (_Float16)W0[i];
        sW1h[i] = (_Float16)W1[i];
    }
    if (tid < NPL) { sb0f[tid] = b0[tid]; sb1f[tid] = b1[tid]; sW2f[tid] = W2[tid]; }
    __syncthreads();

    const int wave = tid >> 6;
    const int lane = tid & 63;
    const int l15  = lane & 15;
    const int kg   = lane >> 4;
    const long wbase = (long)blockIdx.x * MBS + wave * 64;
    const bool active = (wbase < N);

    half8 B0f[4][2], B1f[4][2];
    float bias0[4], bias1[4], w2v[4];
    #pragma unroll
    for (int nt = 0; nt < 4; ++nt) {
        int ch = nt * 16 + l15;
        #pragma unroll
        for (int kh = 0; kh < 2; ++kh) {
            int k = kh * 32 + kg * 8;
            B0f[nt][kh] = *(const half8*)&sW0h[ch * NPL + k];
            B1f[nt][kh] = *(const half8*)&sW1h[ch * NPL + k];
        }
        bias0[nt] = sb0f[ch];
        bias1[nt] = sb1f[ch];
        w2v[nt]   = sW2f[ch];
    }
    __syncthreads();            // weights read; smem region reusable
    if (!active) return;

    _Float16* H = &smem[wave * NPL * HS];

    // ---- layer 0: A from 8 u32 planes ----
    floatx4 acc[4][4];
    #pragma unroll
    for (int mt = 0; mt < 4; ++mt) {
        long pt = wbase + mt * 16 + l15;
        if (pt > N - 1) pt = N - 1;
        const unsigned* p0 = fb + (size_t)(4 * kg) * N + pt;
        const unsigned* p1 = fb + (size_t)(16 + 4 * kg) * N + pt;
        uint4 t0 = make_uint4(p0[0], p0[N], p0[2*(size_t)N], p0[3*(size_t)N]);
        uint4 t1 = make_uint4(p1[0], p1[N], p1[2*(size_t)N], p1[3*(size_t)N]);
        half8 a0 = *reinterpret_cast<half8*>(&t0);
        half8 a1 = *reinterpret_cast<half8*>(&t1);
        #pragma unroll
        for (int nt = 0; nt < 4; ++nt) {
            floatx4 cc = {0.f, 0.f, 0.f, 0.f};
            cc = __builtin_amdgcn_mfma_f32_16x16x32_f16(a0, B0f[nt][0], cc, 0, 0, 0);
            cc = __builtin_amdgcn_mfma_f32_16x16x32_f16(a1, B0f[nt][1], cc, 0, 0, 0);
            acc[mt][nt] = cc;
        }
    }
    #pragma unroll
    for (int mt = 0; mt < 4; ++mt)
        #pragma unroll
        for (int nt = 0; nt < 4; ++nt) {
            int ch = nt * 16 + l15;
            #pragma unroll
            for (int r = 0; r < 4; ++r) {
                float v = fmaxf(acc[mt][nt][r] + bias0[nt], 0.0f);
                H[(mt * 16 + kg * 4 + r) * HS + ch] = (_Float16)v;
            }
        }

    // ---- layer 1 ----
    floatx4 acc2[4][4];
    #pragma unroll
    for (int mt = 0; mt < 4; ++mt) {
        const _Float16* hp = &H[(mt * 16 + l15) * HS];
        half8 a0 = *(const half8*)&hp[kg * 8];
        half8 a1 = *(const half8*)&hp[32 + kg * 8];
        #pragma unroll
        for (int nt = 0; nt < 4; ++nt) {
            floatx4 cc = {0.f, 0.f, 0.f, 0.f};
            cc = __builtin_amdgcn_mfma_f32_16x16x32_f16(a0, B1f[nt][0], cc, 0, 0, 0);
            cc = __builtin_amdgcn_mfma_f32_16x16x32_f16(a1, B1f[nt][1], cc, 0, 0, 0);
            acc2[mt][nt] = cc;
        }
    }

    // ---- layer 2 + 16-lane reduce ----
    float p[4][4];
    #pragma unroll
    for (int mt = 0; mt < 4; ++mt)
        #pragma unroll
        for (int r = 0; r < 4; ++r) p[mt][r] = 0.0f;
    #pragma unroll
    for (int mt = 0; mt < 4; ++mt)
        #pragma unroll
        for (int nt = 0; nt < 4; ++nt)
            #pragma unroll
            for (int r = 0; r < 4; ++r) {
                float v = fmaxf(acc2[mt][nt][r] + bias1[nt], 0.0f);
                p[mt][r] = fmaf(v, w2v[nt], p[mt][r]);
            }
    #pragma unroll
    for (int mt = 0; mt < 4; ++mt)
        #pragma unroll
        for (int r = 0; r < 4; ++r) {
            float s = p[mt][r];
            s += __shfl_xor(s, 1);
            s += __shfl_xor(s, 2);
            s += __shfl_xor(s, 4);
            s += __shfl_xor(s, 8);
            p[mt][r] = s;
        }

    float* HF = (float*)H;
    float ob = b2[0];
    if (l15 == 0) {
        #pragma unroll
        for (int mt = 0; mt < 4; ++mt)
            #pragma unroll
            for (int r = 0; r < 4; ++r)
                HF[mt * 16 + kg * 4 + r] = p[mt][r] + ob;
    }
    long pos = wbase + lane;
    if (pos < N) out[nidx[pos]] = HF[lane];
}

// ---------------------------------------------------------------------------
// Fallback: monolithic fused kernel reading raw f32 grids (no ws needed)
// ---------------------------------------------------------------------------
__global__ __launch_bounds__(256)
void fused_fallback_kernel(const float* __restrict__ x,
                           const float* __restrict__ scales,
                           const float* __restrict__ trans,
                           const float* __restrict__ fg,
                           const float* __restrict__ W0, const float* __restrict__ b0,
                           const float* __restrict__ W1, const float* __restrict__ b1,
                           const float* __restrict__ W2, const float* __restrict__ b2,
                           float* __restrict__ out, int N)
{
    __shared__ float sW0[NPL*NPL], sW1[NPL*NPL], sW2[NPL], sb0[NPL], sb1[NPL];
    __shared__ float sA[NG*3], sB[NG*3];
    const int tid = threadIdx.x;
    for (int i = tid; i < NPL*NPL; i += 256) { sW0[i] = W0[i]; sW1[i] = W1[i]; }
    if (tid < NPL) { sW2[tid] = W2[tid]; sb0[tid] = b0[tid]; sb1[tid] = b1[tid]; }
    if (tid < NG*3) {
        const float k = (1.0f / 1.48f) * 31.5f;
        sA[tid] = scales[tid] * k;
        sB[tid] = trans[tid] * k + 31.5f;
    }
    __syncthreads();
    int n = blockIdx.x * 256 + tid;
    if (n >= N) return;
    float px = x[3*n], py = x[3*n+1], pz = x[3*n+2];
    float feat[2*NG];
    #pragma unroll
    for (int g = 0; g < NG; ++g) {
        float fx = fmaf(px, sA[3*g+0], sB[3*g+0]);
        float fy = fmaf(py, sA[3*g+1], sB[3*g+1]);
        float fz = fmaf(pz, sA[3*g+2], sB[3*g+2]);
        float c0 = 0.f, c1 = 0.f;
        if (fx > -1.f && fx < 64.f && fy > -1.f && fy < 64.f && fz > -1.f && fz < 64.f) {
            float flx = floorf(fx), fly = floorf(fy), flz = floorf(fz);
            int x0 = (int)flx, y0 = (int)fly, z0 = (int)flz;
            float wx = fx-flx, wy = fy-fly, wz = fz-flz;
            float wxa[2], wya[2], wza[2]; int xia[2], yia[2], zia[2];
            wxa[0] = (x0 >= 0  && x0   < DG) ? (1.f-wx) : 0.f;
            wxa[1] = (x0 >= -1 && x0+1 < DG) ? wx : 0.f;
            wya[0] = (y0 >= 0  && y0   < DG) ? (1.f-wy) : 0.f;
            wya[1] = (y0 >= -1 && y0+1 < DG) ? wy : 0.f;
            wza[0] = (z0 >= 0  && z0   < DG) ? (1.f-wz) : 0.f;
            wza[1] = (z0 >= -1 && z0+1 < DG) ? wz : 0.f;
            xia[0] = min(max(x0,0),DG-1); xia[1] = min(max(x0+1,0),DG-1);
            yia[0] = min(max(y0,0),DG-1); yia[1] = min(max(y0+1,0),DG-1);
            zia[0] = min(max(z0,0),DG-1); zia[1] = min(max(z0+1,0),DG-1);
            const float* fr = fg + ((size_t)g << 19);
            #pragma unroll
            for (int dz = 0; dz < 2; ++dz)
                #pragma unroll
                for (int dy = 0; dy < 2; ++dy) {
                    int rowoff = (zia[dz] << 12) + (yia[dy] << 6);
                    float wyz = wya[dy] * wza[dz];
                    #pragma unroll
                    for (int dx = 0; dx < 2; ++dx) {
                        float w = wxa[dx] * wyz;
                        c0 = fmaf(w, fr[rowoff + xia[dx]], c0);
                        c1 = fmaf(w, fr[(1 << 18) + rowoff + xia[dx]], c1);
                    }
                }
        }
        feat[2*g] = c0; feat[2*g+1] = c1;
    }
    float h1[NPL];
    #pragma unroll
    for (int j = 0; j < NPL; j += 2) {
        float a0=0.f,a1=0.f,a2=0.f,a3=0.f;
        const float* r0 = &sW0[j*NPL]; const float* r1 = &sW0[(j+1)*NPL];
        #pragma unroll
        for (int k = 0; k < NPL; k += 2) {
            a0 = fmaf(feat[k],r0[k],a0); a1 = fmaf(feat[k+1],r0[k+1],a1);
            a2 = fmaf(feat[k],r1[k],a2); a3 = fmaf(feat[k+1],r1[k+1],a3);
        }
        h1[j] = fmaxf((a0+a1)+sb0[j],0.f); h1[j+1] = fmaxf((a2+a3)+sb0[j+1],0.f);
    }
    #pragma unroll
    for (int j = 0; j < NPL; j += 2) {
        float a0=0.f,a1=0.f,a2=0.f,a3=0.f;
        const float* r0 = &sW1[j*NPL]; const float* r1 = &sW1[(j+1)*NPL];
        #pragma unroll
        for (int k = 0; k < NPL; k += 2) {
            a0 = fmaf(h1[k],r0[k],a0); a1 = fmaf(h1[k+1],r0[k+1],a1);
            a2 = fmaf(h1[k],r1[k],a2); a3 = fmaf(h1[k+1],r1[k+1],a3);
        }
        feat[j] = fmaxf((a0+a1)+sb1[j],0.f); feat[j+1] = fmaxf((a2+a3)+sb1[j+1],0.f);
    }
    float a0 = 0.f, a1 = 0.f;
    #pragma unroll
    for (int k = 0; k < NPL; k += 2) { a0 = fmaf(feat[k],sW2[k],a0); a1 = fmaf(feat[k+1],sW2[k+1],a1); }
    out[n] = (a0+a1) + b2[0];
}

// ---------------------------------------------------------------------------
extern "C" void kernel_launch(void* const* d_in, const int* in_sizes, int n_in,
                              void* d_out, int out_size, void* d_ws, size_t ws_size,
                              hipStream_t stream) {
    const float* x  = (const float*)d_in[0];
    const float* gs = (const float*)d_in[1];
    const float* gt = (const float*)d_in[2];
    const float* fg = (const float*)d_in[3];
    const float* W0 = (const float*)d_in[4];
    const float* b0 = (const float*)d_in[5];
    const float* W1 = (const float*)d_in[6];
    const float* b1 = (const float*)d_in[7];
    const float* W2 = (const float*)d_in[8];
    const float* b2 = (const float*)d_in[9];
    float* out = (float*)d_out;

    const int N = out_size;

    const size_t pg_bytes    = (size_t)NG * (1 << 18) * 4;                // 33.5 MB
    const size_t fb_bytes    = (size_t)N * NG * 4;                        // 67.1 MB
    const size_t sort_bytes  = (size_t)N * sizeof(float4);                // 8 MB
    const size_t nidx_bytes  = (size_t)N * sizeof(int);                   // 2 MB
    const size_t cs_bytes    = ((NC2 + 1 + 15) & ~15) * sizeof(int);
    const size_t hist_bytes  = (size_t)NC2 * HPAD * sizeof(int);          // 256 KB
    const size_t pairs_bytes = (size_t)NPAIR * 4;                         // 64 KB
    const size_t ctr_bytes   = 64;
    const size_t need_full   = pg_bytes + fb_bytes + sort_bytes + nidx_bytes
                             + cs_bytes + 2 * hist_bytes + pairs_bytes + ctr_bytes;

    if (ws_size >= need_full) {
        char* w = (char*)d_ws;
        unsigned* pg        = (unsigned*)w;  w += pg_bytes;
        unsigned* fb        = (unsigned*)w;  w += fb_bytes;
        float4*   sorted    = (float4*)w;    w += sort_bytes;
        int*      nidx      = (int*)w;       w += nidx_bytes;
        int*      cellstart = (int*)w;       w += cs_bytes;
        int*      ghist     = (int*)w;       w += hist_bytes;
        int*      gcur      = (int*)w;       w += hist_bytes;
        unsigned* pairs     = (unsigned*)w;  w += pairs_bytes;
        int*      counters  = (int*)w;

        int total4 = NG << 16;               // 2M uint4
        int nPackB = total4 / 1024;          // 2048 blocks, 4 uint4/thread
        int nHist  = (N + 2047) / 2048;      // 256
        int nblkS  = (N + BS - 1) / BS;      // 1024

        hipMemsetAsync(ghist, 0, hist_bytes, stream);
        prelude3_kernel<<<nPackB + nHist + 1, 256, 0, stream>>>(
            (const float4*)fg, (uint4*)pg, nPackB, nHist, x, N, ghist,
            gs, gt, pairs, counters);
        scan_kernel<<<1, 1024, 0, stream>>>(ghist, gcur, cellstart);
        scatter_kernel<<<nblkS, BS, 0, stream>>>(x, N, gcur, sorted, nidx);
        gather2_kernel<<<NPAIR, BS, 0, stream>>>(
            sorted, cellstart, pairs, counters, gs, gt, pg, fb, N);
        mlp_kernel<<<(N + MBS - 1) / MBS, MBS, 0, stream>>>(
            fb, nidx, W0, b0, W1, b1, W2, b2, out, N);
    } else {
        fused_fallback_kernel<<<(N + 255) / 256, 256, 0, stream>>>(
            x, gs, gt, fg, W0, b0, W1, b1, W2, b2, out, N);
    }
}